// Round 5
// baseline (106.065 us; speedup 1.0000x reference)
//
#include <hip/hip_runtime.h>
#include <math.h>

// Problem constants
#define NB    256           // N nodes
#define FINN  32            // Fin
#define FOUTN 32            // Fout
#define BT    128           // B*T

// One GEMM: C[i,(bt,o)] = H[i,(e,j)] @ y2[(e,j),(bt,o)],  M=256 N=4096 K=4096.
// Block (bt,kq): all 256 i x 32 o x K-quarter (4 e = 32 ks). y2 produced
// IN-LDS exactly once globally; B-frags fragment-linear (conflict-free).
// v5: 16 waves/block, 1 i-tile/wave, distance-8 register A-ring (8 KiB in
// flight per wave > L2 latency) — attacks the measured ~40 us A-stream
// latency exposure of the distance-2 ring. Raw lgkm barriers keep the ring
// in flight across windows. f32 K-partials [bt][i][kq][o] -> epilogue.

typedef __attribute__((ext_vector_type(8))) short short8;   // 8 bf16 = 4 VGPRs
typedef __attribute__((ext_vector_type(4))) float floatx4;  // MFMA accumulator

#define MFMA16(a,b,c) __builtin_amdgcn_mfma_f32_16x16x32_bf16((a),(b),(c),0,0,0)

// LDS-ordering-only barrier: does NOT drain in-flight global register loads.
#define BARRIER() asm volatile("s_waitcnt lgkmcnt(0)\n\ts_barrier" ::: "memory")

__device__ __forceinline__ float gelu_f(float v) {
    return 0.5f * v * (1.0f + erff(v * 0.70710678118654752f));
}
__device__ __forceinline__ ushort f2bf(float x) {
    union { float f; unsigned u; } v; v.f = x;
    unsigned r = (v.u + 0x7FFFu + ((v.u >> 16) & 1u)) >> 16;
    return (ushort)r;
}
__device__ __forceinline__ uint2 pack4(floatx4 d) {
    uint2 p;
    p.x = (unsigned)f2bf(d[0]) | ((unsigned)f2bf(d[1]) << 16);
    p.y = (unsigned)f2bf(d[2]) | ((unsigned)f2bf(d[3]) << 16);
    return p;
}

// ---------------------------------------------------------------------------
// prep_kernel, grid 289 x 256 thr (verified rounds 2-4, verbatim):
//   [0,128):   Hf  = gelu(adj*w1+b1) in MFMA A-fragment order   (2 MiB)
//   [128,160): xaf = x in MFMA A-fragment order, bf16           (2 MiB)
//   [160,288): bias2g[bt][o] = node_b[o] + (sum_j x[bt,j,:]) @ b2
//   288:       w2f (B-frag order) + nwf (node_w B-frags)
// ---------------------------------------------------------------------------
__global__ __launch_bounds__(256) void prep_kernel(
        const float* __restrict__ x,   const float* __restrict__ adj,
        const float* __restrict__ w1,  const float* __restrict__ b1,
        const float* __restrict__ w2,  const float* __restrict__ b2,
        const float* __restrict__ node_w, const float* __restrict__ node_b,
        ushort* __restrict__ Hf, ushort* __restrict__ w2f,
        ushort* __restrict__ xaf, ushort* __restrict__ nwf,
        float* __restrict__ bias2g) {
    int bid = blockIdx.x;
    int tid = threadIdx.x;

    if (bid < 128) {                    // ---- Hf ----
        __shared__ float adjs[16][264];
        __shared__ float w1s[16], b1s[16];
        int it = bid & 15;
        int kq8 = bid >> 4;             // 0..7
        if (tid < 16) { w1s[tid] = w1[tid]; b1s[tid] = b1[tid]; }
        #pragma unroll
        for (int q = 0; q < 4; ++q) {
            int u = q * 256 + tid;
            int row = u >> 6, c4 = u & 63;
            *(float4*)&adjs[row][c4 * 4] =
                ((const float4*)(adj + ((size_t)it * 16 + row) * 256))[c4];
        }
        __syncthreads();
        #pragma unroll
        for (int q = 0; q < 4; ++q) {
            int u = q * 256 + tid;
            int ks = kq8 * 16 + (u >> 6);
            int lane = u & 63;
            int m = lane & 15, quad = lane >> 4;
            int e = ks >> 3;
            int j0 = (ks & 7) * 32 + quad * 8;
            float w = w1s[e], b = b1s[e];
            ushort tmp[8];
            #pragma unroll
            for (int d = 0; d < 8; ++d)
                tmp[d] = f2bf(gelu_f(adjs[m][j0 + d] * w + b));
            *(int4*)(Hf + (((size_t)it * 128 + ks) * 64 + lane) * 8) = *(int4*)tmp;
        }
        return;
    }
    if (bid < 160) {                    // ---- xaf: wave -> one bt ----
        int wv = tid >> 6, lane = tid & 63, m = lane & 15, quad = lane >> 4;
        int bt = (bid - 128) * 4 + wv;
        #pragma unroll
        for (int jt = 0; jt < 16; ++jt) {
            const float* xs = x + ((size_t)bt * NB + jt * 16 + m) * FINN + quad * 8;
            float4 lo = *(const float4*)xs;
            float4 hi = *(const float4*)(xs + 4);
            ushort tmp[8];
            tmp[0]=f2bf(lo.x); tmp[1]=f2bf(lo.y); tmp[2]=f2bf(lo.z); tmp[3]=f2bf(lo.w);
            tmp[4]=f2bf(hi.x); tmp[5]=f2bf(hi.y); tmp[6]=f2bf(hi.z); tmp[7]=f2bf(hi.w);
            *(int4*)(xaf + (((size_t)bt * 16 + jt) * 64 + lane) * 8) = *(int4*)tmp;
        }
        return;
    }
    if (bid < 288) {                    // ---- bias2g ----
        __shared__ float Sp[8][32];
        __shared__ float Svs[32];
        int bt = bid - 160;
        int f = tid & 31, grp = tid >> 5;
        float s = 0.f;
        for (int j = grp; j < NB; j += 8)
            s += x[((size_t)bt * NB + j) * FINN + f];
        Sp[grp][f] = s;
        __syncthreads();
        if (tid < 32) {
            float s2 = 0.f;
            #pragma unroll
            for (int g = 0; g < 8; ++g) s2 += Sp[g][tid];
            Svs[tid] = s2;
        }
        __syncthreads();
        if (tid < 32) {
            float bb = node_b[tid];
            #pragma unroll
            for (int f2 = 0; f2 < FINN; ++f2)
                bb += Svs[f2] * b2[f2 * FOUTN + tid];
            bias2g[bt * 32 + tid] = bb;
        }
        return;
    }
    // ---- bid == 288: w2f + nwf ----
    for (int s = 0; s < 2048; s += 256) {
        int slot = s + tid;             // (e*2+ot)*64 + lane
        int e = slot >> 7, r = slot & 127;
        int ot = r >> 6, lane = r & 63;
        int m = lane & 15, quad = lane >> 4;
        const float* src = w2 + (size_t)e * 1024 + (quad * 8) * 32 + ot * 16 + m;
        ushort tmp[8];
        #pragma unroll
        for (int i = 0; i < 8; ++i) tmp[i] = f2bf(src[i * 32]);
        *(int4*)(w2f + (size_t)slot * 8) = *(int4*)tmp;
    }
    if (tid < 128) {
        int ot = tid >> 6, lane = tid & 63, m = lane & 15, q = lane >> 4;
        ushort tmp[8];
        #pragma unroll
        for (int d = 0; d < 8; ++d)
            tmp[d] = f2bf(node_w[(q * 8 + d) * 32 + ot * 16 + m]);
        *(int4*)(nwf + tid * 8) = *(int4*)tmp;
    }
}

// ---------------------------------------------------------------------------
// main_kernel: grid (128 bt, 4 kq) x 1024 thr (16 waves). Wave -> 1 i-tile
// (it = wv). 4 windows (1 e each), window loop unroll-1. Per step: consume
// areg[kk] (loaded 8 steps earlier), refill ring slot, 2 linear ds_read_b128,
// 2 MFMA. Produce: wave wv -> jt = wv, 2 MFMA + 2 ds_write_b64 per window
// (verified jt-generic scatter: jp=jt>>1, qc=(jt&1)*2+(quad>>1), dp=(quad&1)*4).
// Raw lgkm barriers keep the A-ring in flight. Partials -> Cp [bt][i][kq][o].
// ---------------------------------------------------------------------------
__global__ __launch_bounds__(1024, 4) void main_kernel(
        const ushort* __restrict__ Hf,  const ushort* __restrict__ w2f,
        const ushort* __restrict__ xaf, float* __restrict__ Cp) {
    __shared__ ushort Bsl[2][8][2][512];    // 32 KiB [buf][jp][oh][frag]

    int bt   = blockIdx.x;              // 0..127
    int kq   = blockIdx.y;              // 0..3
    int tid  = threadIdx.x;
    int wv   = tid >> 6;                // 0..15
    int lane = tid & 63;
    int m    = lane & 15;
    int quad = lane >> 4;

    // produce input: x A-frag for jt = wv (verified mapping)
    short8 xfr = *(const short8*)(xaf + (((size_t)bt * 16 + wv) * 64 + lane) * 8);
    const int qc  = (wv & 1) * 2 + (quad >> 1);   // B-frag scatter coords
    const int dp  = (quad & 1) * 4;
    const int jp0 = wv >> 1;

    const ushort* Ha = Hf + (size_t)wv * 128 * 512 + (size_t)lane * 8;
    const ushort* Wl = w2f + (size_t)lane * 8;

    short8 areg[8];                     // distance-8 A-prefetch ring
    floatx4 acc[2] = {};                // [oh]

    #define ALOAD(slot, s_)                                                   \
    {                                                                         \
        int ks_ = kq * 32 + (s_); if (ks_ > 127) ks_ = 127;                   \
        areg[slot] = *(const short8*)(Ha + (size_t)ks_ * 512);                \
    }
    #define PRODUCE(bp, wf0, wf1)                                             \
    {                                                                         \
        floatx4 z = {0.f, 0.f, 0.f, 0.f};                                     \
        floatx4 d0 = MFMA16(xfr, wf0, z);                                     \
        floatx4 d1 = MFMA16(xfr, wf1, z);                                     \
        *(uint2*)((bp) + jp0 * 1024 +       (qc * 16 + m) * 8 + dp) = pack4(d0); \
        *(uint2*)((bp) + jp0 * 1024 + 512 + (qc * 16 + m) * 8 + dp) = pack4(d1); \
    }

    // prologue: fill ring s=0..7; produce window 0 into buf 0
    #pragma unroll
    for (int s = 0; s < 8; ++s) ALOAD(s, s);
    {
        short8 wf0 = *(const short8*)(Wl + (size_t)(kq * 4) * 1024);
        short8 wf1 = *(const short8*)(Wl + (size_t)(kq * 4) * 1024 + 512);
        PRODUCE((ushort*)Bsl, wf0, wf1);
    }
    BARRIER();

    #pragma unroll 1
    for (int w = 0; w < 4; ++w) {
        // next-window w2 frags (clamped dummy at w=3; L2-resident)
        int en = kq * 4 + ((w < 3) ? (w + 1) : 3);
        short8 wf0 = *(const short8*)(Wl + (size_t)en * 1024);
        short8 wf1 = *(const short8*)(Wl + (size_t)en * 1024 + 512);

        ushort* Bb = (ushort*)Bsl + (w & 1) * 8192;       // consume buf
        #pragma unroll
        for (int kk = 0; kk < 8; ++kk) {
            short8 a = areg[kk];                // loaded 8 steps ago
            ALOAD(kk, w * 8 + kk + 8);          // refill for +8 (renamed reg)
            short8 b0 = *(const short8*)(Bb + kk * 1024 + lane * 8);
            short8 b1 = *(const short8*)(Bb + kk * 1024 + 512 + lane * 8);
            acc[0] = MFMA16(a, b0, acc[0]);
            acc[1] = MFMA16(a, b1, acc[1]);
        }
        if (w < 3) {
            ushort* Bn = (ushort*)Bsl + ((w + 1) & 1) * 8192;
            PRODUCE(Bn, wf0, wf1);
        }
        BARRIER();                      // A-ring stays in flight (lgkm only)
    }

    // ---- store f32 K-partials: Cp[bt][i][kq][o] (64B-coalesced) ----
    #pragma unroll
    for (int oh = 0; oh < 2; ++oh)
        #pragma unroll
        for (int r = 0; r < 4; ++r) {
            int i = wv * 16 + quad * 4 + r;
            Cp[(((size_t)bt * NB + i) * 4 + kq) * FOUTN + oh * 16 + m]
                = acc[oh][r];
        }
    #undef ALOAD
    #undef PRODUCE
}

// ---------------------------------------------------------------------------
// epilogue (verified round-4, verbatim): grid (128 bt, 2 ih) x 256 thr.
// out = gelu(sum_kq Cp + x@node_w + bias2).
// ---------------------------------------------------------------------------
__global__ __launch_bounds__(256) void epi_kernel(
        const ushort* __restrict__ xaf, const ushort* __restrict__ nwf,
        const float* __restrict__ bias2g, const float* __restrict__ Cp,
        float* __restrict__ out) {
    int bt   = blockIdx.x;
    int ih   = blockIdx.y;
    int tid  = threadIdx.x;
    int wv   = tid >> 6;
    int lane = tid & 63;
    int m    = lane & 15;
    int quad = lane >> 4;

    short8 nb0 = *(const short8*)(nwf + (size_t)lane * 8);
    short8 nb1 = *(const short8*)(nwf + ((size_t)64 + lane) * 8);

    #pragma unroll
    for (int t = 0; t < 2; ++t) {
        int it = ih * 8 + wv * 2 + t;
        short8 xa = *(const short8*)(xaf + (((size_t)bt * 16 + it) * 64 + lane) * 8);
        #pragma unroll
        for (int tn = 0; tn < 2; ++tn) {
            floatx4 z = {0.f, 0.f, 0.f, 0.f};
            floatx4 ea = MFMA16(xa, tn ? nb1 : nb0, z);
            float bz = bias2g[bt * 32 + tn * 16 + m];
            #pragma unroll
            for (int r = 0; r < 4; ++r) {
                int i = it * 16 + quad * 4 + r;
                float s = ea[r] + bz;
                #pragma unroll
                for (int kqi = 0; kqi < 4; ++kqi)
                    s += Cp[(((size_t)bt * NB + i) * 4 + kqi) * FOUTN + tn * 16 + m];
                out[((size_t)bt * NB + i) * FOUTN + tn * 16 + m] = gelu_f(s);
            }
        }
    }
}

// ---------------------------------------------------------------------------
extern "C" void kernel_launch(void* const* d_in, const int* in_sizes, int n_in,
                              void* d_out, int out_size, void* d_ws, size_t ws_size,
                              hipStream_t stream) {
    const float* x      = (const float*)d_in[0];
    const float* adj    = (const float*)d_in[1];
    const float* w1     = (const float*)d_in[2];
    const float* b1     = (const float*)d_in[3];
    const float* w2     = (const float*)d_in[4];
    const float* b2     = (const float*)d_in[5];
    const float* node_w = (const float*)d_in[6];
    const float* node_b = (const float*)d_in[7];
    float* out = (float*)d_out;

    // Workspace (~20.1 MiB):
    ushort* Hf     = (ushort*)d_ws;                  // 16*128*512  = 2 MiB
    ushort* w2f    = Hf + (size_t)16 * 128 * 512;    // 16*2*512    = 32 KiB
    ushort* xaf    = w2f + 16384;                    // 128*16*512  = 2 MiB
    ushort* nwf    = xaf + (size_t)128 * 16 * 512;   // 2*512       = 2 KiB
    float*  bias2g = (float*)(nwf + 1024);           // 128*32      = 16 KiB
    float*  Cp     = bias2g + 128 * 32;              // 128*256*4*32= 16 MiB

    hipLaunchKernelGGL(prep_kernel, dim3(289), dim3(256), 0, stream,
                       x, adj, w1, b1, w2, b2, node_w, node_b,
                       Hf, w2f, xaf, nwf, bias2g);
    hipLaunchKernelGGL(main_kernel, dim3(BT, 4), dim3(1024), 0, stream,
                       Hf, w2f, xaf, Cp);
    hipLaunchKernelGGL(epi_kernel, dim3(BT, 2), dim3(256), 0, stream,
                       xaf, nwf, bias2g, Cp, out);
}